// Round 20
// baseline (258.173 us; speedup 1.0000x reference)
//
#include <hip/hip_runtime.h>
#include <hip/hip_bf16.h>

// Problem constants
#define NB 4
#define NT 256
#define NU 100
#define NH 512      // H_ENC = H_DEC = 512
#define NI 512      // INNER
#define NV 1024     // VOCAB
#define MROWS (NB * NT * NU)   // 102400 joint rows

typedef __attribute__((ext_vector_type(4))) float f32x4;
typedef __attribute__((ext_vector_type(8))) __bf16 bf16x8;

// round-to-nearest-even f32 -> bf16 bits
static __device__ __forceinline__ unsigned int f2bf(float f) {
  unsigned int u = __float_as_uint(f);
  return (u + 0x7FFFu + ((u >> 16) & 1u)) >> 16;
}

// tanh(x) = 1 - 2/(1+e^{2x})
static __device__ __forceinline__ float fast_tanh(float x) {
  float e = __expf(2.f * x);
  return 1.f - 2.f * __builtin_amdgcn_rcpf(1.f + e);
}

// packed RNE f32x2 -> bf16x2 (single instruction)
static __device__ __forceinline__ unsigned int cvt_pk_bf16(float lo, float hi) {
  unsigned int r;
  asm("v_cvt_pk_bf16_f32 %0, %1, %2" : "=v"(r) : "v"(lo), "v"(hi));
  return r;
}

// ---------------------------------------------------------------------------
// Merged prep kernel. Grid (55, 8):
//  bx < 23: projections  pe[r][i] = enc[r][:] . W1[i][0:512]     (r < 1024)
//                        pd[r][i] = dec[r][:] . W1[i][512:1024]  (r < 400)
//  bx >= 23: W2 f32 -> bf16 pre-fragged for 16x16x32 B operands, BK=32:
//    chunk c (16B) = [nt 4][kt 16][cb 16][lq 4][lr 16] ->
//      col = nt*256 + cb*16 + lr,  k = kt*32 + lq*8
// ---------------------------------------------------------------------------
__global__ __launch_bounds__(256) void prep_kernel(
    const float* __restrict__ enc, const float* __restrict__ dec,
    const float* __restrict__ W1, const float* __restrict__ W2,
    float* __restrict__ pe, float* __restrict__ pd,
    unsigned short* __restrict__ w2f) {
  const int bx = blockIdx.x;
  const int tx = threadIdx.x;
  if (bx >= 23) {
    int c = ((bx - 23) * 8 + blockIdx.y) * 256 + tx;  // 65536 chunks
    int lr = c & 15, lq = (c >> 4) & 3;
    int cb = (c >> 6) & 15, kt = (c >> 10) & 15, nt = (c >> 14) & 3;
    int v = nt * 256 + cb * 16 + lr;
    int k = kt * 32 + lq * 8;
    const float* src = W2 + (size_t)v * NI + k;
    float4 a = *(const float4*)src;
    float4 b = *(const float4*)(src + 4);
    uint4 o;
    o.x = f2bf(a.x) | (f2bf(a.y) << 16);
    o.y = f2bf(a.z) | (f2bf(a.w) << 16);
    o.z = f2bf(b.x) | (f2bf(b.y) << 16);
    o.w = f2bf(b.z) | (f2bf(b.w) << 16);
    *(uint4*)(w2f + (size_t)c * 8) = o;
    return;
  }
  __shared__ float As[64][17];
  __shared__ float Bs[64][17];
  const float* A;
  float* P;
  int Mrows, colOff, row0;
  if (bx < 16) { A = enc; P = pe; Mrows = NB * NT; colOff = 0;  row0 = bx * 64; }
  else         { A = dec; P = pd; Mrows = NB * NU; colOff = NH; row0 = (bx - 16) * 64; }
  const int col0 = blockIdx.y * 64;
  const int tr = tx >> 4, tc = tx & 15;
  const int lr = tx >> 2, lc = (tx & 3) * 4;
  float acc[4][4] = {};
  for (int k0 = 0; k0 < NH; k0 += 16) {
    float4 av = make_float4(0.f, 0.f, 0.f, 0.f);
    if (row0 + lr < Mrows)
      av = *(const float4*)(A + (size_t)(row0 + lr) * NH + k0 + lc);
    float4 bv = *(const float4*)(W1 + (size_t)(col0 + lr) * (NH + NH) + colOff + k0 + lc);
    As[lr][lc] = av.x; As[lr][lc + 1] = av.y; As[lr][lc + 2] = av.z; As[lr][lc + 3] = av.w;
    Bs[lr][lc] = bv.x; Bs[lr][lc + 1] = bv.y; Bs[lr][lc + 2] = bv.z; Bs[lr][lc + 3] = bv.w;
    __syncthreads();
#pragma unroll
    for (int kk = 0; kk < 16; ++kk) {
      float a4[4], b4[4];
#pragma unroll
      for (int i = 0; i < 4; ++i) { a4[i] = As[tr * 4 + i][kk]; b4[i] = Bs[tc * 4 + i][kk]; }
#pragma unroll
      for (int i = 0; i < 4; ++i)
#pragma unroll
        for (int j = 0; j < 4; ++j) acc[i][j] = fmaf(a4[i], b4[j], acc[i][j]);
    }
    __syncthreads();
  }
#pragma unroll
  for (int i = 0; i < 4; ++i) {
    int r = row0 + tr * 4 + i;
    if (r < Mrows) {
#pragma unroll
      for (int j = 0; j < 4; ++j)
        P[(size_t)r * NI + col0 + tc * 4 + j] = acc[i][j];
    }
  }
}

// ---------------------------------------------------------------------------
// Fused joint GEMM — de-confounded geometry:
//   wave tile 64x64 (TA:matrix ratio < 1, 256B-sector-clean stores)
//   AND 64 KB LDS / <=128 VGPR (2 blocks/CU, 16 waves/CU, 4/SIMD).
// Block: 512 thr / 8 waves side-by-side in N; block = 64 rows x 512 cols
// (half vocab; nh = bid&1). Each wave spans the block's FULL 64-row M.
// Phase 0: A panel (64 x 512) = tanh(pe+pd+b1) -> 64 KB LDS, granule
//   swizzle g8 ^ (row&7). tanh computed 2x per row (one per col-half) —
//   ~+25 us VALU aggregate, overlapped on the separate pipe.
// K-loop: just 16 steps of BK=32, NO in-loop epilogues (each wave owns its
//   64 cols for the whole K). B: even/odd register sets (4 x bf16x8),
//   use-then-reload one step ahead. Per wave-step: 4 B-loads + 4 A ds_reads
//   + 16 MFMA  ->  per-CU TA ~512 cy < matrix ~1240 cy per step-round.
// Single store phase at kernel end: +b2, fp32, 256B/row contiguous per wave.
// ---------------------------------------------------------------------------
__global__ __launch_bounds__(512, 4) void fused_joint_kernel(
    const float* __restrict__ pe, const float* __restrict__ pd,
    const float* __restrict__ b1, const unsigned short* __restrict__ w2f,
    const float* __restrict__ b2, float* __restrict__ out) {
  __shared__ unsigned char ldsA[65536];    // 64 rows x 512 k bf16, swizzled
  const int tx = threadIdx.x;
  const int R0 = (blockIdx.x >> 1) * 64;
  const int nh = blockIdx.x & 1;           // vocab half
  const int lane = tx & 63, wid = tx >> 6; // wave owns cols wid*64..+63
  const int lr = lane & 15, lq = lane >> 4;

  // B fragment base (shorts): chunk = [nt][kt][cb][lq][lr];
  // nt = nh*2 + (wid>>2), cb = (wid&3)*4 + nf  (nf stride = 64 chunks)
  const unsigned short* w2base =
      w2f + ((size_t)(nh * 2 + (wid >> 2)) * 16384 +
             (size_t)((wid & 3) * 4) * 64 + lq * 16 + lr) * 8;
#define LOADB(DST, KT) do {                                                   \
    const unsigned short* s_ = w2base + ((size_t)(KT) << 13);                 \
    DST##0 = *(const bf16x8*)(s_);                                            \
    DST##1 = *(const bf16x8*)(s_ + 512);                                      \
    DST##2 = *(const bf16x8*)(s_ + 1024);                                     \
    DST##3 = *(const bf16x8*)(s_ + 1536);                                     \
  } while (0)

  bf16x8 bA0, bA1, bA2, bA3, bB0, bB1, bB2, bB3;
  LOADB(bA, 0);                            // in flight through phase 0

  // ---- Phase 0: A panel (64 x 512) = tanh(pe+pd+b1) -> ldsA ----
#pragma unroll 2
  for (int pass = 0; pass < 8; ++pass) {
    int idx = pass * 512 + tx;             // 4096 granules of 8 elems
    int row = idx >> 6;                    // 0..63
    int g8 = idx & 63;                     // granule within row
    int i0 = g8 * 8;
    int grow = R0 + row;
    int b = grow / (NT * NU);
    int rem = grow - b * (NT * NU);
    int t = rem / NU;
    int u = rem - t * NU;
    const float* peP = pe + (size_t)(b * NT + t) * NI + i0;
    const float* pdP = pd + (size_t)(b * NU + u) * NI + i0;
    float4 p0 = *(const float4*)peP, p1 = *(const float4*)(peP + 4);
    float4 q0 = *(const float4*)pdP, q1 = *(const float4*)(pdP + 4);
    float4 c0 = *(const float4*)(b1 + i0), c1 = *(const float4*)(b1 + i0 + 4);
    uint4 pk;
    pk.x = cvt_pk_bf16(fast_tanh(p0.x + q0.x + c0.x), fast_tanh(p0.y + q0.y + c0.y));
    pk.y = cvt_pk_bf16(fast_tanh(p0.z + q0.z + c0.z), fast_tanh(p0.w + q0.w + c0.w));
    pk.z = cvt_pk_bf16(fast_tanh(p1.x + q1.x + c1.x), fast_tanh(p1.y + q1.y + c1.y));
    pk.w = cvt_pk_bf16(fast_tanh(p1.z + q1.z + c1.z), fast_tanh(p1.w + q1.w + c1.w));
    *(uint4*)(ldsA + row * 1024 + ((g8 ^ (row & 7)) << 4)) = pk;
  }
  __syncthreads();                         // the ONLY barrier

  f32x4 acc[4][4];
#pragma unroll
  for (int mf = 0; mf < 4; ++mf)
#pragma unroll
    for (int nf = 0; nf < 4; ++nf)
#pragma unroll
      for (int z = 0; z < 4; ++z) acc[mf][nf][z] = 0.f;

  // A frag: row = mf*16 + lr (all waves share the block's 64-row M)
  const int rx = lr & 7;

#define COMPUTE(BV, KT) do {                                                  \
    bf16x8 af_[4];                                                            \
    const int so_ = (((KT) * 4 + lq) ^ rx) << 4;                              \
    _Pragma("unroll")                                                         \
    for (int mf = 0; mf < 4; ++mf)                                            \
      af_[mf] = *(const bf16x8*)(ldsA + (mf * 16 + lr) * 1024 + so_);         \
    __builtin_amdgcn_s_setprio(1);                                            \
    _Pragma("unroll")                                                         \
    for (int mf = 0; mf < 4; ++mf) {                                          \
      acc[mf][0] = __builtin_amdgcn_mfma_f32_16x16x32_bf16(af_[mf], BV##0, acc[mf][0], 0, 0, 0); \
      acc[mf][1] = __builtin_amdgcn_mfma_f32_16x16x32_bf16(af_[mf], BV##1, acc[mf][1], 0, 0, 0); \
      acc[mf][2] = __builtin_amdgcn_mfma_f32_16x16x32_bf16(af_[mf], BV##2, acc[mf][2], 0, 0, 0); \
      acc[mf][3] = __builtin_amdgcn_mfma_f32_16x16x32_bf16(af_[mf], BV##3, acc[mf][3], 0, 0, 0); \
    }                                                                         \
    __builtin_amdgcn_s_setprio(0);                                            \
  } while (0)

  for (int kt = 0; kt < 16; kt += 2) {
    LOADB(bB, kt + 1);                     // prefetch odd step
    COMPUTE(bA, kt);
    if (kt + 2 < 16) LOADB(bA, kt + 2);    // prefetch next even step
    COMPUTE(bB, kt + 1);
  }
#undef COMPUTE
#undef LOADB

  // single epilogue: + b2, fp32 stores; per row, this wave writes a full
  // 256B sector (cols wid*64..+63) via 4 consecutive 16-lane segments.
#pragma unroll
  for (int nf = 0; nf < 4; ++nf) {
    int col = nh * 512 + wid * 64 + nf * 16 + lr;
    float bb = b2[col];
#pragma unroll
    for (int mf = 0; mf < 4; ++mf) {
#pragma unroll
      for (int j = 0; j < 4; ++j) {
        int grow = R0 + mf * 16 + lq * 4 + j;
        out[(size_t)grow * NV + col] = acc[mf][nf][j] + bb;
      }
    }
  }
}

extern "C" void kernel_launch(void* const* d_in, const int* in_sizes, int n_in,
                              void* d_out, int out_size, void* d_ws, size_t ws_size,
                              hipStream_t stream) {
  const float* enc = (const float*)d_in[0];
  const float* dec = (const float*)d_in[1];
  const float* W1  = (const float*)d_in[2];
  const float* b1  = (const float*)d_in[3];
  const float* W2  = (const float*)d_in[4];
  const float* b2  = (const float*)d_in[5];
  float* out = (float*)d_out;
  char* ws = (char*)d_ws;

  float* pe = (float*)ws;                                   // 2 MB
  float* pd = (float*)(ws + (2u << 20));                    // 0.8 MB
  unsigned short* w2f = (unsigned short*)(ws + (3u << 20)); // 1 MB, fragged

  prep_kernel<<<dim3(55, 8), 256, 0, stream>>>(enc, dec, W1, W2, pe, pd, w2f);
  fused_joint_kernel<<<(MROWS / 64) * 2, 512, 0, stream>>>(pe, pd, b1, w2f, b2, out);
}